// Round 7
// baseline (1170.626 us; speedup 1.0000x reference)
//
#include <hip/hip_runtime.h>
#include <cstdint>
#include <cstddef>
#include <math.h>

#define NB   4096
#define NT   512
#define NRNN 25
#define NHID 20

typedef float v2f __attribute__((ext_vector_type(2)));

// R17: software-pipelined dual-batch. 2 batches per 32-lane group, phase-
// interleaved half a feval apart: every fpost(gX) is separated from its
// fpre(sgX) by the OTHER batch's fpost (~70cyc VALU) -> ~90% of the ~120cyc
// LDS round trip is hidden INSIDE one wave. 512 blocks x 128 thr = 1024
// waves = 1/SIMD (R13's failure was coincident gather windows, not ILP).
constexpr int GROUPS = 4;                    // 32-lane groups per block
constexpr int BPG    = 2;                    // batches per group
constexpr int BLOCK  = 32 * GROUPS;          // 128 threads
constexpr int GRID   = NB / (GROUPS * BPG);  // 512 blocks

constexpr size_t PREDX_N  = (size_t)NB * NT * 2;
constexpr size_t Z0_OFF   = PREDX_N;
constexpr size_t MEAN_OFF = Z0_OFF + (size_t)NB * 4;
constexpr size_t LV_OFF   = MEAN_OFF + (size_t)NB * 4;

__device__ __forceinline__ float bf2f(uint16_t u) {
    union { uint32_t i; float f; } c; c.i = ((uint32_t)u) << 16; return c.f;
}
__device__ __forceinline__ uint16_t f2bf(float f) {
    union { float ff; uint32_t i; } c; c.ff = f;
    return (uint16_t)((c.i + 0x7fffu + ((c.i >> 16) & 1u)) >> 16);  // RNE
}
__device__ __forceinline__ float ldin(const void* p, int i, bool bf) {
    return bf ? bf2f(((const uint16_t*)p)[i]) : ((const float*)p)[i];
}
__device__ __forceinline__ double ldind(const void* p, int i, bool bf) {
    return (double)ldin(p, i, bf);
}
__device__ __forceinline__ void wbar() {
    __asm__ volatile("" ::: "memory");
    __builtin_amdgcn_wave_barrier();
    __asm__ volatile("" ::: "memory");
}
__device__ __forceinline__ v2f pkfma(v2f a, v2f b, v2f c) {
#if __has_builtin(__builtin_elementwise_fma)
    return __builtin_elementwise_fma(a, b, c);
#else
    v2f r; r.x = __builtin_fmaf(a.x, b.x, c.x); r.y = __builtin_fmaf(a.y, b.y, c.y);
    return r;
#endif
}
// fast ELU tail via native v_exp_f32 (validated R10)
__device__ __forceinline__ float fast_elu(float x) {
    return x > 0.f ? x : __expf(x) - 1.f;
}
// fast tanh: 1 - 2/(e^{2x}+1); ~5 inst, abs err ~1e-6, graceful at +-inf
__device__ __forceinline__ float fast_tanh(float x) {
    float e = __expf(2.f * x);
    return 1.f - 2.f * __builtin_amdgcn_rcpf(e + 1.f);
}
template <int CTRL>
__device__ __forceinline__ float dpp_movf(float v) {
    return __int_as_float(__builtin_amdgcn_update_dpp(
        0, __float_as_int(v), CTRL, 0xf, 0xf, true));
}
// xor-16 pair sum: v[l] + v[l^16] per lane, within each 32-lane group.
// R12: two-result permlane16_swap builtin (alias-safe). VALU pipe, no lgkmcnt.
__device__ __forceinline__ float xor16_sum(float v) {
#if __has_builtin(__builtin_amdgcn_permlane16_swap)
    unsigned u = __float_as_uint(v);
    auto r = __builtin_amdgcn_permlane16_swap(u, u, false, false);
    return __uint_as_float(r[0]) + __uint_as_float(r[1]);
#else
    return v + __int_as_float(__builtin_amdgcn_ds_swizzle(__float_as_int(v), 0x401F));
#endif
}

__global__ void __launch_bounds__(BLOCK)
node_kernel(const void* __restrict__ trajs,   // (B,T,2)
            const void* __restrict__ ts,      // (T)
            const void* __restrict__ eps,     // (B,4)
            const void* __restrict__ i2h_w, const void* __restrict__ i2h_b,
            const void* __restrict__ h2o_w, const void* __restrict__ h2o_b,
            const void* __restrict__ f1w, const void* __restrict__ f1b,
            const void* __restrict__ f2w, const void* __restrict__ f2b,
            const void* __restrict__ f3w, const void* __restrict__ f3b,
            const void* __restrict__ d1w, const void* __restrict__ d1b,
            const void* __restrict__ d2w, const void* __restrict__ d2b,
            void* __restrict__ out)
{
    // dtype probe: samp_ts[0]=0.0, samp_ts[1]=0.01.
    const bool bf = (((const uint32_t*)ts)[0] != 0u);

    __shared__ __align__(16) float s_x[GROUPS][BPG][NT * 2];  // 32 KiB
    __shared__ float s_dt[NT];
    __shared__ __align__(16) float s_g[GROUPS][BPG][32];      // gather bufs

    const int tid  = threadIdx.x;
    const int grp  = tid >> 5;
    const int lane = tid & 31;
    const int bA   = (blockIdx.x * GROUPS + grp) * BPG;
    const int bB   = bA + 1;
    float* sgA = &s_g[grp][0][0];
    float* sgB = &s_g[grp][1][0];
    const bool lo1 = (lane & 1) != 0;
    const bool lo2 = (lane & 2) != 0;

    for (int i = tid; i < NT - 1; i += BLOCK)
        s_dt[i] = ldin(ts, i + 1, bf) - ldin(ts, i, bf);

    if (bf) {
        const uint32_t* trA = (const uint32_t*)trajs + (size_t)bA * NT;
        const uint32_t* trB = trA + NT;   // bB = bA+1, rows contiguous
        #pragma unroll 4
        for (int k = 0; k < NT / 32; ++k) {
            uint32_t vA = trA[lane + 32 * k];
            uint32_t vB = trB[lane + 32 * k];
            *(float2*)&s_x[grp][0][(size_t)(lane + 32 * k) * 2] =
                make_float2(bf2f((uint16_t)(vA & 0xffffu)), bf2f((uint16_t)(vA >> 16)));
            *(float2*)&s_x[grp][1][(size_t)(lane + 32 * k) * 2] =
                make_float2(bf2f((uint16_t)(vB & 0xffffu)), bf2f((uint16_t)(vB >> 16)));
        }
    } else {
        const float2* trA = (const float2*)trajs + (size_t)bA * NT;
        const float2* trB = trA + NT;
        #pragma unroll 4
        for (int k = 0; k < NT / 32; ++k) {
            *(float2*)&s_x[grp][0][(size_t)(lane + 32 * k) * 2] = trA[lane + 32 * k];
            *(float2*)&s_x[grp][1][(size_t)(lane + 32 * k) * 2] = trB[lane + 32 * k];
        }
    }
    sgA[lane] = 0.f;
    sgB[lane] = 0.f;
    __syncthreads();

    // ---------------- Phase 1: reverse RNN, phase-pipelined A/B ----------------
    float whs[25];
    #pragma unroll
    for (int i = 0; i < 25; ++i) whs[i] = 0.f;
    float wx0 = 0.f, wx1 = 0.f, wb = 0.f;
    if (lane < NRNN) {
        wx0 = ldin(i2h_w, lane, bf);
        wx1 = ldin(i2h_w, NRNN + lane, bf);
        #pragma unroll
        for (int i = 0; i < NRNN; ++i) whs[i] = ldin(i2h_w, (2 + i) * NRNN + lane, bf);
        wb = ldin(i2h_b, lane, bf);
    }
    v2f wxp = {wx0, wx1};
    v2f whp[12];
    #pragma unroll
    for (int m = 0; m < 12; ++m) { whp[m].x = whs[2 * m]; whp[m].y = whs[2 * m + 1]; }
    const float w24 = whs[24];

    // issue h-gather: write h, issue 6 b128 reads + scalar h24 (R16 layout)
    auto rnn_issue = [&](float* sgp, float h, float4 (&g)[6], float& h24) {
        sgp[lane] = h;                   // lanes>=25 keep h=0
        wbar();
        const float4* g4 = (const float4*)sgp;
        g[0] = g4[0]; g[1] = g4[1]; g[2] = g4[2];
        g[3] = g4[3]; g[4] = g4[4]; g[5] = g4[5];
        h24 = sgp[24];
        wbar();
    };
    auto rnn_dot = [&](const float4 (&g)[6], float h24, v2f xa) -> float {
        v2f p0 = {g[0].x, g[0].y}, p1 = {g[0].z, g[0].w};
        v2f p2 = {g[1].x, g[1].y}, p3 = {g[1].z, g[1].w};
        v2f p4 = {g[2].x, g[2].y}, p5 = {g[2].z, g[2].w};
        v2f p6 = {g[3].x, g[3].y}, p7 = {g[3].z, g[3].w};
        v2f p8 = {g[4].x, g[4].y}, p9 = {g[4].z, g[4].w};
        v2f pA = {g[5].x, g[5].y}, pB = {g[5].z, g[5].w};
        v2f A = xa;
        v2f B = p0 * whp[0];
        A = pkfma(p1, whp[1], A);
        B = pkfma(p2, whp[2], B);
        A = pkfma(p3, whp[3], A);
        B = pkfma(p4, whp[4], B);
        A = pkfma(p5, whp[5], A);
        B = pkfma(p6, whp[6], B);
        A = pkfma(p7, whp[7], A);
        B = pkfma(p8, whp[8], B);
        A = pkfma(p9, whp[9], A);
        B = pkfma(pA, whp[10], B);
        A = pkfma(pB, whp[11], A);
        B.x = __builtin_fmaf(h24, w24, B.x);   // bit-identical h24 term
        return fast_tanh(((A.x + B.x) + (A.y + B.y)) + wb);
    };

    float2 xcA = *(const float2*)&s_x[grp][0][2 * (NT - 1)];
    float2 xcB = *(const float2*)&s_x[grp][1][2 * (NT - 1)];
    v2f xaA; xaA.x = xcA.x * wxp.x; xaA.y = xcA.y * wxp.y;
    v2f xaB; xaB.x = xcB.x * wxp.x; xaB.y = xcB.y * wxp.y;
    float hA = 0.f, hB = 0.f;
    float4 gA6[6], gB6[6]; float h24A = 0.f, h24B = 0.f;
    rnn_issue(sgA, hA, gA6, h24A);           // prologue: A gather in flight
    for (int t = NT - 1; t >= 0; --t) {
        rnn_issue(sgB, hB, gB6, h24B);       // B gather in flight
        int tn = t > 0 ? t - 1 : 0;
        float2 xnA = *(const float2*)&s_x[grp][0][2 * tn];
        float2 xnB = *(const float2*)&s_x[grp][1][2 * tn];
        hA = rnn_dot(gA6, h24A, xaA);        // consumes gather issued LAST iter
        rnn_issue(sgA, hA, gA6, h24A);       // A gather for next iter
        v2f xanA; xanA.x = xnA.x * wxp.x; xanA.y = xnA.y * wxp.y;
        v2f xanB; xanB.x = xnB.x * wxp.x; xanB.y = xnB.y * wxp.y;
        hB = rnn_dot(gB6, h24B, xaB);        // ~85cyc after its issue
        xaA = xanA; xaB = xanB;
    }

    // ---------------- Phase 2: h2o + reparameterize (f64, one-time) ----------------
    double zdA[4], zdB[4];
    auto phase2 = [&](float h, int bb, double (&zd)[4]) {
        double hl[NRNN];
        #pragma unroll
        for (int j = 0; j < NRNN; ++j) hl[j] = (double)__shfl(h, j, 32);

        double o = 0.0;
        if (lane < 8) {
            double a0 = 0, a1 = 0, a2 = 0, a3 = 0;
            #pragma unroll
            for (int i = 0; i < 24; i += 4) {
                a0 += hl[i + 0] * ldind(h2o_w, (i + 0) * 8 + lane, bf);
                a1 += hl[i + 1] * ldind(h2o_w, (i + 1) * 8 + lane, bf);
                a2 += hl[i + 2] * ldind(h2o_w, (i + 2) * 8 + lane, bf);
                a3 += hl[i + 3] * ldind(h2o_w, (i + 3) * 8 + lane, bf);
            }
            a0 += hl[24] * ldind(h2o_w, 24 * 8 + lane, bf);
            o = ((a0 + a1) + (a2 + a3)) + ldind(h2o_b, lane, bf);
        }
        double mean[4], lv[4];
        #pragma unroll
        for (int c = 0; c < 4; ++c) {
            mean[c] = __shfl(o, c, 32);
            lv[c]   = __shfl(o, 4 + c, 32);
        }
        double ep[4];
        if (bf) {
            const uint32_t* e32 = (const uint32_t*)eps + (size_t)bb * 2;
            uint32_t e0 = e32[0], e1 = e32[1];
            ep[0] = bf2f((uint16_t)(e0 & 0xffffu)); ep[1] = bf2f((uint16_t)(e0 >> 16));
            ep[2] = bf2f((uint16_t)(e1 & 0xffffu)); ep[3] = bf2f((uint16_t)(e1 >> 16));
        } else {
            const float* ef = (const float*)eps + (size_t)bb * 4;
            #pragma unroll
            for (int c = 0; c < 4; ++c) ep[c] = ef[c];
        }
        #pragma unroll
        for (int c = 0; c < 4; ++c)
            zd[c] = ep[c] * exp(0.5 * lv[c]) + mean[c];

        if (lane < 4) {
            double zv  = lane == 0 ? zd[0] : lane == 1 ? zd[1] : lane == 2 ? zd[2] : zd[3];
            double mv  = lane == 0 ? mean[0] : lane == 1 ? mean[1] : lane == 2 ? mean[2] : mean[3];
            double lvv = lane == 0 ? lv[0] : lane == 1 ? lv[1] : lane == 2 ? lv[2] : lv[3];
            if (bf) {
                uint16_t* o16 = (uint16_t*)out;
                o16[Z0_OFF   + (size_t)bb * 4 + lane] = f2bf((float)zv);
                o16[MEAN_OFF + (size_t)bb * 4 + lane] = f2bf((float)mv);
                o16[LV_OFF   + (size_t)bb * 4 + lane] = f2bf((float)lvv);
            } else {
                float* of = (float*)out;
                of[Z0_OFF   + (size_t)bb * 4 + lane] = (float)zv;
                of[MEAN_OFF + (size_t)bb * 4 + lane] = (float)mv;
                of[LV_OFF   + (size_t)bb * 4 + lane] = (float)lvv;
            }
        }
    };
    phase2(hA, bA, zdA);
    phase2(hB, bB, zdB);

    // ---------------- Phase 3: RK4 ODE, 8-phase A/B pipeline ----------------
    float f2s[NHID], f3r[4] = {0,0,0,0};
    float f1bb = 0.f, f2bb = 0.f, d1bb = 0.f, d2r0 = 0.f, d2r1 = 0.f;
    v2f f1p0 = {0,0}, f1p1 = {0,0}, d1p0 = {0,0}, d1p1 = {0,0};
    #pragma unroll
    for (int i = 0; i < NHID; ++i) f2s[i] = 0.f;
    if (lane < NHID) {
        f1p0.x = ldin(f1w, 0 * NHID + lane, bf);
        f1p0.y = ldin(f1w, 1 * NHID + lane, bf);
        f1p1.x = ldin(f1w, 2 * NHID + lane, bf);
        f1p1.y = ldin(f1w, 3 * NHID + lane, bf);
        f1bb = ldin(f1b, lane, bf);
        #pragma unroll
        for (int i = 0; i < NHID; ++i) f2s[i] = ldin(f2w, i * NHID + lane, bf);
        f2bb = ldin(f2b, lane, bf);
        #pragma unroll
        for (int c = 0; c < 4; ++c) f3r[c] = ldin(f3w, lane * 4 + c, bf);
        d1p0.x = ldin(d1w, 0 * NHID + lane, bf);
        d1p0.y = ldin(d1w, 1 * NHID + lane, bf);
        d1p1.x = ldin(d1w, 2 * NHID + lane, bf);
        d1p1.y = ldin(d1w, 3 * NHID + lane, bf);
        d1bb = ldin(d1b, lane, bf);
        d2r0 = ldin(d2w, lane * 2 + 0, bf);
        d2r1 = ldin(d2w, lane * 2 + 1, bf);
    }
    v2f f2p[10];
    #pragma unroll
    for (int m = 0; m < 10; ++m) { f2p[m].x = f2s[2 * m]; f2p[m].y = f2s[2 * m + 1]; }
    v2f f3rp0 = {f3r[0], f3r[1]}, f3rp1 = {f3r[2], f3r[3]};
    v2f d2rp  = {d2r0, d2r1};
    float f3bc[4];
    #pragma unroll
    for (int c = 0; c < 4; ++c) f3bc[c] = ldin(f3b, c, bf);
    const float f3bl = lo2 ? (lo1 ? f3bc[3] : f3bc[2]) : (lo1 ? f3bc[1] : f3bc[0]);
    const float d2b0 = ldin(d2b, 0, bf), d2b1 = ldin(d2b, 1, bf);
    const float d2bl = lo1 ? d2b1 : d2b0;

    // quad-spread state (R15/R16): one double per lane, component lane&3.
    auto zq_init = [&](double (&zd)[4]) -> double {
        double tlo = lo1 ? zd[1] : zd[0];
        double thi = lo1 ? zd[3] : zd[2];
        return lo2 ? thi : tlo;
    };
    double zqA = zq_init(zdA), zqB = zq_init(zdB);
    float zqfA = (float)zqA, zqfB = (float)zqB;

    auto qdot4 = [&](float tq, v2f w01, v2f w23, float bias) -> float {
        float acc = bias;
        acc = __builtin_fmaf(dpp_movf<0xFF>(tq), w23.y, acc);
        acc = __builtin_fmaf(dpp_movf<0xAA>(tq), w23.x, acc);
        acc = __builtin_fmaf(dpp_movf<0x55>(tq), w01.y, acc);
        acc = __builtin_fmaf(dpp_movf<0x00>(tq), w01.x, acc);
        return acc;
    };

    auto fpre = [&](float* sgp, float tq, float4 (&g)[5]) {
        float u1 = fast_elu(qdot4(tq, f1p0, f1p1, f1bb));   // lanes>=20 -> 0
        sgp[lane] = u1;
        wbar();
        const float4* g4 = (const float4*)sgp;
        g[0] = g4[0]; g[1] = g4[1]; g[2] = g4[2]; g[3] = g4[3]; g[4] = g4[4];
        wbar();
    };
    auto fpost = [&](const float4 (&g)[5]) -> float {
        v2f q0 = {g[0].x, g[0].y}, q1 = {g[0].z, g[0].w};
        v2f q2 = {g[1].x, g[1].y}, q3 = {g[1].z, g[1].w};
        v2f q4 = {g[2].x, g[2].y}, q5 = {g[2].z, g[2].w};
        v2f q6 = {g[3].x, g[3].y}, q7 = {g[3].z, g[3].w};
        v2f q8 = {g[4].x, g[4].y}, q9 = {g[4].z, g[4].w};
        v2f A = q0 * f2p[0];
        v2f B = q1 * f2p[1];
        A = pkfma(q2, f2p[2], A);
        B = pkfma(q3, f2p[3], B);
        A = pkfma(q4, f2p[4], A);
        B = pkfma(q5, f2p[5], B);
        A = pkfma(q6, f2p[6], A);
        B = pkfma(q7, f2p[7], B);
        A = pkfma(q8, f2p[8], A);
        B = pkfma(q9, f2p[9], B);
        float u2 = fast_elu(((A.x + B.x) + (A.y + B.y)) + f2bb);
        v2f uu = {u2, u2};
        v2f q01 = uu * f3rp0, q23 = uu * f3rp1;
        float x0 = q01.x + dpp_movf<0xB1>(q01.x);
        float x1 = q01.y + dpp_movf<0xB1>(q01.y);
        float x2 = q23.x + dpp_movf<0xB1>(q23.x);
        float x3 = q23.y + dpp_movf<0xB1>(q23.y);
        float a  = lo1 ? x1 : x0;
        float c  = lo1 ? x3 : x2;
        a += dpp_movf<0x4E>(a);
        c += dpp_movf<0x4E>(c);
        float v = lo2 ? c : a;
        v += dpp_movf<0x124>(v);
        v += dpp_movf<0x128>(v);
        v = xor16_sum(v);
        return v + f3bl;    // quad form: quad-pos c holds output c
    };

    auto dec_a = [&](float tq) -> float {
        float r = qdot4(tq, d1p0, d1p1, d1bb);
        r = fmaxf(r, 0.f);
        v2f rr = {r, r};
        v2f pp = rr * d2rp;
        float x0 = pp.x + dpp_movf<0xB1>(pp.x);
        float x1 = pp.y + dpp_movf<0xB1>(pp.y);
        float a  = lo1 ? x1 : x0;
        a += dpp_movf<0x4E>(a);
        return a;
    };
    auto dec_b1 = [&](float a) -> float {
        a += dpp_movf<0x124>(a);
        a += dpp_movf<0x128>(a);
        return a;
    };
    auto dec_b2 = [&](float a) -> float2 {
        a = xor16_sum(a);
        a += d2bl;
        float a1v = dpp_movf<0x55>(a);
        return make_float2(a, a1v);
    };
    auto dec_store = [&](float2 av, int t, int bb) {
        if (lane == 0) {
            if (bf) {
                uint32_t wv = (uint32_t)f2bf(av.x) | ((uint32_t)f2bf(av.y) << 16);
                *(uint32_t*)((uint16_t*)out + ((size_t)bb * NT + t) * 2) = wv;
            } else {
                ((float2*)out)[(size_t)bb * NT + t] = av;
            }
        }
    };

    float4 gA[5], gB[5];
    float dtc = s_dt[0];
    fpre(sgA, zqfA, gA);                     // prologue: A.k1 reads in flight
    for (int s = 0; s < NT - 1; ++s) {
        float dt = dtc;
        // [1] B.k1 pre | A dec_a | A.k1 post
        fpre(sgB, zqfB, gB);
        float daA = dec_a(zqfA);
        float k1A = fpost(gA);
        float hdt = 0.5f * dt;
        float t1A = __builtin_fmaf(hdt, k1A, zqfA);
        // [2] A.k2 pre | B dec_a | B.k1 post
        fpre(sgA, t1A, gA);
        float daB = dec_a(zqfB);
        float k1B = fpost(gB);
        float t1B = __builtin_fmaf(hdt, k1B, zqfB);
        // [3] B.k2 pre | A dec_b1 | A.k2 post
        fpre(sgB, t1B, gB);
        daA = dec_b1(daA);
        float k2A = fpost(gA);
        float t2A = __builtin_fmaf(hdt, k2A, zqfA);
        // [4] A.k3 pre | B dec_b1 | B.k2 post
        fpre(sgA, t2A, gA);
        daB = dec_b1(daB);
        float k2B = fpost(gB);
        float t2B = __builtin_fmaf(hdt, k2B, zqfB);
        // [5] B.k3 pre | A dec_b2 | A.k3 post
        fpre(sgB, t2B, gB);
        float2 dvA = dec_b2(daA);
        float k3A = fpost(gA);
        float t3A = __builtin_fmaf(dt, k3A, zqfA);
        // [6] A.k4 pre | B dec_b2, A store | B.k3 post
        fpre(sgA, t3A, gA);
        float2 dvB = dec_b2(daB);
        dec_store(dvA, s, bA);
        float k3B = fpost(gB);
        float t3B = __builtin_fmaf(dt, k3B, zqfB);
        // [7] B.k4 pre | B store, dt prefetch, A combine prep | A.k4 post
        fpre(sgB, t3B, gB);
        dec_store(dvB, s, bB);
        dtc = s_dt[s + 1];                   // last iter: dead value, in-bounds
        float mA  = k2A + k3A;
        float dt6 = dt * (1.f / 6.f);
        float k4A = fpost(gA);
        float sqA = __builtin_fmaf(2.f, mA, k1A) + k4A;
        zqA += (double)(dt6 * sqA);          // f64 state chain
        zqfA = (float)zqA;
        // [8] A.k1' pre (next step) | B combine prep | B.k4 post
        fpre(sgA, zqfA, gA);                 // extra on last iter: harmless
        float mB  = k2B + k3B;
        float k4B = fpost(gB);
        float sqB = __builtin_fmaf(2.f, mB, k1B) + k4B;
        zqB += (double)(dt6 * sqB);
        zqfB = (float)zqB;
    }
    dec_store(dec_b2(dec_b1(dec_a(zqfA))), NT - 1, bA);   // final outputs
    dec_store(dec_b2(dec_b1(dec_a(zqfB))), NT - 1, bB);
}

extern "C" void kernel_launch(void* const* d_in, const int* in_sizes, int n_in,
                              void* d_out, int out_size, void* d_ws, size_t ws_size,
                              hipStream_t stream) {
    (void)in_sizes; (void)n_in; (void)out_size; (void)d_ws; (void)ws_size;
    node_kernel<<<GRID, BLOCK, 0, stream>>>(
        d_in[0],  // samp_trajs
        d_in[1],  // samp_ts
        d_in[2],  // epsilon
        d_in[3],  d_in[4],   // i2h
        d_in[5],  d_in[6],   // h2o
        d_in[7],  d_in[8],   // f1
        d_in[9],  d_in[10],  // f2
        d_in[11], d_in[12],  // f3
        d_in[13], d_in[14],  // d1
        d_in[15], d_in[16],  // d2
        d_out);
}

// Round 8
// 648.383 us; speedup vs baseline: 1.8055x; 1.8055x over previous
//
#include <hip/hip_runtime.h>
#include <cstdint>
#include <cstddef>
#include <math.h>

#define NB   4096
#define NT   512
#define NRNN 25
#define NHID 20

typedef float v2f __attribute__((ext_vector_type(2)));

constexpr int GROUPS = 8;            // batches per block (one per 32-lane group)
constexpr int BLOCK  = 32 * GROUPS;  // 256 threads
constexpr int GRID   = NB / GROUPS;  // 512 blocks -> 2048 waves, 2/SIMD (R10 anchor)

constexpr size_t PREDX_N  = (size_t)NB * NT * 2;
constexpr size_t Z0_OFF   = PREDX_N;
constexpr size_t MEAN_OFF = Z0_OFF + (size_t)NB * 4;
constexpr size_t LV_OFF   = MEAN_OFF + (size_t)NB * 4;

__device__ __forceinline__ float bf2f(uint16_t u) {
    union { uint32_t i; float f; } c; c.i = ((uint32_t)u) << 16; return c.f;
}
__device__ __forceinline__ uint16_t f2bf(float f) {
    union { float ff; uint32_t i; } c; c.ff = f;
    return (uint16_t)((c.i + 0x7fffu + ((c.i >> 16) & 1u)) >> 16);  // RNE
}
__device__ __forceinline__ float ldin(const void* p, int i, bool bf) {
    return bf ? bf2f(((const uint16_t*)p)[i]) : ((const float*)p)[i];
}
__device__ __forceinline__ double ldind(const void* p, int i, bool bf) {
    return (double)ldin(p, i, bf);
}
// R18: the old wbar() (asm volatile ""::: "memory" + wave_barrier) is treated
// as a memory op by the waitcnt pass -> it DRAINED lgkmcnt to 0 right after
// the gather issue, serializing the LDS round trip before any filler ran
// (retro-explains R14/R16 "filler neutral" and R13/R17 pipeline nulls).
// sched_barrier(0) pins instruction order WITHOUT memory semantics: the
// compiler then places a precise counted lgkmcnt at first use, after filler.
__device__ __forceinline__ void sbar() {
    __builtin_amdgcn_sched_barrier(0);
}
__device__ __forceinline__ v2f pkfma(v2f a, v2f b, v2f c) {
#if __has_builtin(__builtin_elementwise_fma)
    return __builtin_elementwise_fma(a, b, c);
#else
    v2f r; r.x = __builtin_fmaf(a.x, b.x, c.x); r.y = __builtin_fmaf(a.y, b.y, c.y);
    return r;
#endif
}
// fast ELU tail via native v_exp_f32 (validated R10)
__device__ __forceinline__ float fast_elu(float x) {
    return x > 0.f ? x : __expf(x) - 1.f;
}
// fast tanh: 1 - 2/(e^{2x}+1); ~5 inst, abs err ~1e-6, graceful at +-inf
__device__ __forceinline__ float fast_tanh(float x) {
    float e = __expf(2.f * x);
    return 1.f - 2.f * __builtin_amdgcn_rcpf(e + 1.f);
}
template <int CTRL>
__device__ __forceinline__ float dpp_movf(float v) {
    return __int_as_float(__builtin_amdgcn_update_dpp(
        0, __float_as_int(v), CTRL, 0xf, 0xf, true));
}
// xor-16 pair sum: v[l] + v[l^16] per lane, within each 32-lane group.
// R12: two-result permlane16_swap builtin (alias-safe). VALU pipe, no lgkmcnt.
__device__ __forceinline__ float xor16_sum(float v) {
#if __has_builtin(__builtin_amdgcn_permlane16_swap)
    unsigned u = __float_as_uint(v);
    auto r = __builtin_amdgcn_permlane16_swap(u, u, false, false);
    return __uint_as_float(r[0]) + __uint_as_float(r[1]);
#else
    return v + __int_as_float(__builtin_amdgcn_ds_swizzle(__float_as_int(v), 0x401F));
#endif
}

__global__ void __launch_bounds__(BLOCK)
node_kernel(const void* __restrict__ trajs,   // (B,T,2)
            const void* __restrict__ ts,      // (T)
            const void* __restrict__ eps,     // (B,4)
            const void* __restrict__ i2h_w, const void* __restrict__ i2h_b,
            const void* __restrict__ h2o_w, const void* __restrict__ h2o_b,
            const void* __restrict__ f1w, const void* __restrict__ f1b,
            const void* __restrict__ f2w, const void* __restrict__ f2b,
            const void* __restrict__ f3w, const void* __restrict__ f3b,
            const void* __restrict__ d1w, const void* __restrict__ d1b,
            const void* __restrict__ d2w, const void* __restrict__ d2b,
            void* __restrict__ out)
{
    // dtype probe: samp_ts[0]=0.0, samp_ts[1]=0.01.
    const bool bf = (((const uint32_t*)ts)[0] != 0u);

    __shared__ __align__(16) float s_x[GROUPS][NT * 2];  // read-only after sync
    __shared__ float s_dt[NT];
    __shared__ __align__(16) float s_g[GROUPS][32];      // per-group gather buf

    const int tid  = threadIdx.x;
    const int grp  = tid >> 5;
    const int lane = tid & 31;
    const int b    = blockIdx.x * GROUPS + grp;
    float* sg = &s_g[grp][0];
    const bool lo1 = (lane & 1) != 0;
    const bool lo2 = (lane & 2) != 0;

    for (int i = tid; i < NT - 1; i += BLOCK)
        s_dt[i] = ldin(ts, i + 1, bf) - ldin(ts, i, bf);

    if (bf) {
        const uint32_t* tr32 = (const uint32_t*)trajs + (size_t)b * NT;
        #pragma unroll 4
        for (int k = 0; k < NT / 32; ++k) {
            uint32_t v = tr32[lane + 32 * k];
            *(float2*)&s_x[grp][(size_t)(lane + 32 * k) * 2] =
                make_float2(bf2f((uint16_t)(v & 0xffffu)), bf2f((uint16_t)(v >> 16)));
        }
    } else {
        const float2* trf = (const float2*)trajs + (size_t)b * NT;
        #pragma unroll 4
        for (int k = 0; k < NT / 32; ++k)
            *(float2*)&s_x[grp][(size_t)(lane + 32 * k) * 2] = trf[lane + 32 * k];
    }
    sg[lane] = 0.f;
    __syncthreads();

    // R11/R14: de-correlate co-resident waves (one-time random phase offset).
    {
        unsigned wid = ((unsigned)blockIdx.x << 2) | ((unsigned)tid >> 6);
        unsigned r = (wid * 0x9E3779B9u) >> 27;  // 0..31
        while (r--) __builtin_amdgcn_s_sleep(1);
    }

    // ---------------- Phase 1: reverse RNN (f32, packed dots, fast tanh) ----------------
    float whs[25];
    #pragma unroll
    for (int i = 0; i < 25; ++i) whs[i] = 0.f;
    float wx0 = 0.f, wx1 = 0.f, wb = 0.f;
    if (lane < NRNN) {
        wx0 = ldin(i2h_w, lane, bf);
        wx1 = ldin(i2h_w, NRNN + lane, bf);
        #pragma unroll
        for (int i = 0; i < NRNN; ++i) whs[i] = ldin(i2h_w, (2 + i) * NRNN + lane, bf);
        wb = ldin(i2h_b, lane, bf);
    }
    v2f wxp = {wx0, wx1};
    v2f whp[12];
    #pragma unroll
    for (int m = 0; m < 12; ++m) { whp[m].x = whs[2 * m]; whp[m].y = whs[2 * m + 1]; }
    const float w24 = whs[24];

    // software-pipelined x: next-x product computed in the gather window
    float2 xc = *(const float2*)&s_x[grp][2 * (NT - 1)];
    v2f xa; xa.x = xc.x * wxp.x; xa.y = xc.y * wxp.y;
    float h = 0.f;
    for (int t = NT - 1; t >= 0; --t) {
        sg[lane] = h;                    // lanes>=25 keep h=0
        // write->read ordering via aliasing (same __shared__ object) + DS
        // in-order; no memory fence needed, so no forced lgkmcnt drain.
        const float4* g4 = (const float4*)sg;
        float4 v0 = g4[0], v1 = g4[1], v2 = g4[2], v3 = g4[3];
        float4 v4 = g4[4], v5 = g4[5];
        float h24 = sg[24];
        int tn = t > 0 ? t - 1 : 0;
        float2 xn = *(const float2*)&s_x[grp][2 * tn];  // queued behind gather
        sbar();                          // pin issue order; no waitcnt forced
        __builtin_amdgcn_s_setprio(0);   // window: don't outcompete other wave
        v2f xan; xan.x = xn.x * wxp.x; xan.y = xn.y * wxp.y;  // next-iter seed
        v2f p0 = {v0.x, v0.y}, p1 = {v0.z, v0.w}, p2 = {v1.x, v1.y}, p3 = {v1.z, v1.w};
        v2f p4 = {v2.x, v2.y}, p5 = {v2.z, v2.w}, p6 = {v3.x, v3.y}, p7 = {v3.z, v3.w};
        v2f p8 = {v4.x, v4.y}, p9 = {v4.z, v4.w}, pA = {v5.x, v5.y}, pB = {v5.z, v5.w};
        __builtin_amdgcn_s_setprio(1);   // dependent chain: run at high prio
        // sequential-consume 2-acc (incremental lgkmcnt waits)
        v2f A = xa;
        v2f B = p0 * whp[0];
        A = pkfma(p1, whp[1], A);
        B = pkfma(p2, whp[2], B);
        A = pkfma(p3, whp[3], A);
        B = pkfma(p4, whp[4], B);
        A = pkfma(p5, whp[5], A);
        B = pkfma(p6, whp[6], B);
        A = pkfma(p7, whp[7], A);
        B = pkfma(p8, whp[8], B);
        A = pkfma(p9, whp[9], A);
        B = pkfma(pA, whp[10], B);
        A = pkfma(pB, whp[11], A);
        B.x = __builtin_fmaf(h24, w24, B.x);   // bit-identical h24 term
        h = fast_tanh(((A.x + B.x) + (A.y + B.y)) + wb);
        xa = xan;
    }

    // ---------------- Phase 2: h2o + reparameterize (f64, one-time) ----------------
    double hl[NRNN];
    #pragma unroll
    for (int j = 0; j < NRNN; ++j) hl[j] = (double)__shfl(h, j, 32);

    double o = 0.0;
    if (lane < 8) {
        double a0 = 0, a1 = 0, a2 = 0, a3 = 0;
        #pragma unroll
        for (int i = 0; i < 24; i += 4) {
            a0 += hl[i + 0] * ldind(h2o_w, (i + 0) * 8 + lane, bf);
            a1 += hl[i + 1] * ldind(h2o_w, (i + 1) * 8 + lane, bf);
            a2 += hl[i + 2] * ldind(h2o_w, (i + 2) * 8 + lane, bf);
            a3 += hl[i + 3] * ldind(h2o_w, (i + 3) * 8 + lane, bf);
        }
        a0 += hl[24] * ldind(h2o_w, 24 * 8 + lane, bf);
        o = ((a0 + a1) + (a2 + a3)) + ldind(h2o_b, lane, bf);
    }
    double mean[4], lv[4];
    #pragma unroll
    for (int c = 0; c < 4; ++c) {
        mean[c] = __shfl(o, c, 32);
        lv[c]   = __shfl(o, 4 + c, 32);
    }
    double ep[4];
    if (bf) {
        const uint32_t* e32 = (const uint32_t*)eps + (size_t)b * 2;
        uint32_t e0 = e32[0], e1 = e32[1];
        ep[0] = bf2f((uint16_t)(e0 & 0xffffu)); ep[1] = bf2f((uint16_t)(e0 >> 16));
        ep[2] = bf2f((uint16_t)(e1 & 0xffffu)); ep[3] = bf2f((uint16_t)(e1 >> 16));
    } else {
        const float* ef = (const float*)eps + (size_t)b * 4;
        #pragma unroll
        for (int c = 0; c < 4; ++c) ep[c] = ef[c];
    }
    double zd[4];
    #pragma unroll
    for (int c = 0; c < 4; ++c)
        zd[c] = ep[c] * exp(0.5 * lv[c]) + mean[c];

    if (lane < 4) {
        double zv  = lane == 0 ? zd[0] : lane == 1 ? zd[1] : lane == 2 ? zd[2] : zd[3];
        double mv  = lane == 0 ? mean[0] : lane == 1 ? mean[1] : lane == 2 ? mean[2] : mean[3];
        double lvv = lane == 0 ? lv[0] : lane == 1 ? lv[1] : lane == 2 ? lv[2] : lv[3];
        if (bf) {
            uint16_t* o16 = (uint16_t*)out;
            o16[Z0_OFF   + (size_t)b * 4 + lane] = f2bf((float)zv);
            o16[MEAN_OFF + (size_t)b * 4 + lane] = f2bf((float)mv);
            o16[LV_OFF   + (size_t)b * 4 + lane] = f2bf((float)lvv);
        } else {
            float* of = (float*)out;
            of[Z0_OFF   + (size_t)b * 4 + lane] = (float)zv;
            of[MEAN_OFF + (size_t)b * 4 + lane] = (float)mv;
            of[LV_OFF   + (size_t)b * 4 + lane] = (float)lvv;
        }
    }

    // ---------------- Phase 3: RK4 ODE (quad-spread f64 state) ----------------
    float f2s[NHID], f3r[4] = {0,0,0,0};
    float f1bb = 0.f, f2bb = 0.f, d1bb = 0.f, d2r0 = 0.f, d2r1 = 0.f;
    v2f f1p0 = {0,0}, f1p1 = {0,0}, d1p0 = {0,0}, d1p1 = {0,0};
    #pragma unroll
    for (int i = 0; i < NHID; ++i) f2s[i] = 0.f;
    if (lane < NHID) {
        f1p0.x = ldin(f1w, 0 * NHID + lane, bf);
        f1p0.y = ldin(f1w, 1 * NHID + lane, bf);
        f1p1.x = ldin(f1w, 2 * NHID + lane, bf);
        f1p1.y = ldin(f1w, 3 * NHID + lane, bf);
        f1bb = ldin(f1b, lane, bf);
        #pragma unroll
        for (int i = 0; i < NHID; ++i) f2s[i] = ldin(f2w, i * NHID + lane, bf);
        f2bb = ldin(f2b, lane, bf);
        #pragma unroll
        for (int c = 0; c < 4; ++c) f3r[c] = ldin(f3w, lane * 4 + c, bf);
        d1p0.x = ldin(d1w, 0 * NHID + lane, bf);
        d1p0.y = ldin(d1w, 1 * NHID + lane, bf);
        d1p1.x = ldin(d1w, 2 * NHID + lane, bf);
        d1p1.y = ldin(d1w, 3 * NHID + lane, bf);
        d1bb = ldin(d1b, lane, bf);
        d2r0 = ldin(d2w, lane * 2 + 0, bf);
        d2r1 = ldin(d2w, lane * 2 + 1, bf);
    }
    v2f f2p[10];
    #pragma unroll
    for (int m = 0; m < 10; ++m) { f2p[m].x = f2s[2 * m]; f2p[m].y = f2s[2 * m + 1]; }
    v2f f3rp0 = {f3r[0], f3r[1]}, f3rp1 = {f3r[2], f3r[3]};
    v2f d2rp  = {d2r0, d2r1};
    float f3bc[4];
    #pragma unroll
    for (int c = 0; c < 4; ++c) f3bc[c] = ldin(f3b, c, bf);
    const float f3bl = lo2 ? (lo1 ? f3bc[3] : f3bc[2]) : (lo1 ? f3bc[1] : f3bc[0]);
    const float d2b0 = ldin(d2b, 0, bf), d2b1 = ldin(d2b, 1, bf);
    const float d2bl = lo1 ? d2b1 : d2b0;

    // R15/R16: quad-spread state (one double per lane, component lane&3);
    // DPP-folded broadcast consumption via scalar fmac chains.
    double zq;
    {
        double tlo = lo1 ? zd[1] : zd[0];
        double thi = lo1 ? zd[3] : zd[2];
        zq = lo2 ? thi : tlo;
    }
    float zqf = (float)zq;

    auto qdot4 = [&](float tq, v2f w01, v2f w23, float bias) -> float {
        float acc = bias;
        acc = __builtin_fmaf(dpp_movf<0xFF>(tq), w23.y, acc);
        acc = __builtin_fmaf(dpp_movf<0xAA>(tq), w23.x, acc);
        acc = __builtin_fmaf(dpp_movf<0x55>(tq), w01.y, acc);
        acc = __builtin_fmaf(dpp_movf<0x00>(tq), w01.x, acc);
        return acc;
    };

    // fpre: f1 dot + elu + ds_write + issue the 5 gather reads. R18: no
    // memory fence after the reads — sched_barrier(0) pins issue order and
    // the waitcnt pass places a precise counted lgkmcnt at first use in
    // fpost, AFTER the filler that sits between fpre and fpost.
    auto fpre = [&](float tq, float4 (&g)[5]) {
        float u1 = fast_elu(qdot4(tq, f1p0, f1p1, f1bb));   // lanes>=20 -> 0
        sg[lane] = u1;
        const float4* g4 = (const float4*)sg;
        g[0] = g4[0]; g[1] = g4[1]; g[2] = g4[2]; g[3] = g4[3]; g[4] = g4[4];
        sbar();
        __builtin_amdgcn_s_setprio(0);
    };
    auto fpost = [&](const float4 (&g)[5]) -> float {
        __builtin_amdgcn_s_setprio(1);
        v2f q0 = {g[0].x, g[0].y}, q1 = {g[0].z, g[0].w};
        v2f q2 = {g[1].x, g[1].y}, q3 = {g[1].z, g[1].w};
        v2f q4 = {g[2].x, g[2].y}, q5 = {g[2].z, g[2].w};
        v2f q6 = {g[3].x, g[3].y}, q7 = {g[3].z, g[3].w};
        v2f q8 = {g[4].x, g[4].y}, q9 = {g[4].z, g[4].w};
        // sequential-consume 2-acc (incremental lgkmcnt waits)
        v2f A = q0 * f2p[0];
        v2f B = q1 * f2p[1];
        A = pkfma(q2, f2p[2], A);
        B = pkfma(q3, f2p[3], B);
        A = pkfma(q4, f2p[4], A);
        B = pkfma(q5, f2p[5], B);
        A = pkfma(q6, f2p[6], A);
        B = pkfma(q7, f2p[7], B);
        A = pkfma(q8, f2p[8], A);
        B = pkfma(q9, f2p[9], B);
        float u2 = fast_elu(((A.x + B.x) + (A.y + B.y)) + f2bb);
        // fused 4-way allreduce: quad-transpose (DPP) + row_ror + permlane16.
        // Result stays in quad form: quad-pos c holds output c.
        v2f uu = {u2, u2};
        v2f q01 = uu * f3rp0, q23 = uu * f3rp1;
        float x0 = q01.x + dpp_movf<0xB1>(q01.x);
        float x1 = q01.y + dpp_movf<0xB1>(q01.y);
        float x2 = q23.x + dpp_movf<0xB1>(q23.x);
        float x3 = q23.y + dpp_movf<0xB1>(q23.y);
        float a  = lo1 ? x1 : x0;
        float c  = lo1 ? x3 : x2;
        a += dpp_movf<0x4E>(a);
        c += dpp_movf<0x4E>(c);
        float v = lo2 ? c : a;
        v += dpp_movf<0x124>(v);
        v += dpp_movf<0x128>(v);
        v = xor16_sum(v);
        return v + f3bl;
    };

    // decode split 4-way across the k1/k2/k3/k4 gather windows
    auto dec_a = [&](float tq) -> float {
        float r = qdot4(tq, d1p0, d1p1, d1bb);
        r = fmaxf(r, 0.f);                       // relu; lanes>=20 give 0
        v2f rr = {r, r};
        v2f pp = rr * d2rp;
        float x0 = pp.x + dpp_movf<0xB1>(pp.x);
        float x1 = pp.y + dpp_movf<0xB1>(pp.y);
        float a  = lo1 ? x1 : x0;
        a += dpp_movf<0x4E>(a);
        return a;
    };
    auto dec_b1 = [&](float a) -> float {
        a += dpp_movf<0x124>(a);
        a += dpp_movf<0x128>(a);
        return a;
    };
    auto dec_b2 = [&](float a) -> float2 {
        a = xor16_sum(a);
        a += d2bl;
        float a1v = dpp_movf<0x55>(a);
        return make_float2(a, a1v);
    };
    auto dec_store = [&](float2 av, int t) {
        if (lane == 0) {
            if (bf) {
                uint32_t wv = (uint32_t)f2bf(av.x) | ((uint32_t)f2bf(av.y) << 16);
                *(uint32_t*)((uint16_t*)out + ((size_t)b * NT + t) * 2) = wv;
            } else {
                ((float2*)out)[(size_t)b * NT + t] = av;
            }
        }
    };

    float4 g[5];
    for (int s = 0; s < NT - 1; ++s) {
        float dt = s_dt[s];
        // ---- k1 ----
        fpre(zqf, g);
        float da = dec_a(zqf);               // filler in k1 read window
        float k1q = fpost(g);
        float hdt = 0.5f * dt;
        float t1 = __builtin_fmaf(hdt, k1q, zqf);
        // ---- k2 ----
        fpre(t1, g);
        da = dec_b1(da);                     // filler in k2 read window
        float k2q = fpost(g);
        float t2 = __builtin_fmaf(hdt, k2q, zqf);
        // ---- k3 ----
        fpre(t2, g);
        float2 dv = dec_b2(da);              // filler in k3 read window
        float k3q = fpost(g);
        float t3 = __builtin_fmaf(dt, k3q, zqf);
        // ---- k4 ----
        fpre(t3, g);
        dec_store(dv, s);                    // filler in k4 read window (store)
        float mq  = k2q + k3q;
        float dt6 = dt * (1.f / 6.f);
        float k4q = fpost(g);
        // k1 + 2*(k2+k3) + k4, scalar lane-slice (bit-identical: m+m exact)
        float sq = __builtin_fmaf(2.f, mq, k1q) + k4q;
        float iq = dt6 * sq;
        zq += (double)iq;                    // f64 state chain (one add/lane)
        zqf = (float)zq;
    }
    dec_store(dec_b2(dec_b1(dec_a(zqf))), NT - 1);   // final output
}

extern "C" void kernel_launch(void* const* d_in, const int* in_sizes, int n_in,
                              void* d_out, int out_size, void* d_ws, size_t ws_size,
                              hipStream_t stream) {
    (void)in_sizes; (void)n_in; (void)out_size; (void)d_ws; (void)ws_size;
    node_kernel<<<GRID, BLOCK, 0, stream>>>(
        d_in[0],  // samp_trajs
        d_in[1],  // samp_ts
        d_in[2],  // epsilon
        d_in[3],  d_in[4],   // i2h
        d_in[5],  d_in[6],   // h2o
        d_in[7],  d_in[8],   // f1
        d_in[9],  d_in[10],  // f2
        d_in[11], d_in[12],  // f3
        d_in[13], d_in[14],  // d1
        d_in[15], d_in[16],  // d2
        d_out);
}